// Round 5
// baseline (383.246 us; speedup 1.0000x reference)
//
#include <hip/hip_runtime.h>

// Problem constants (match reference)
#define N_NODES    1000000
#define N_EDGES    16000000
#define D          30
#define WINDOW     5
#define DEG_THRESH 10

// ---- binning params ----
#define P_PARTS    31                 // partitions of 32768 nodes
#define PART_BITS  15
#define PART_SIZE  32768
#define BUF_CAP    512                // LDS staging entries per bucket
#define BIN_BLOCKS 256
#define BIN_THREADS 1024
#define BIN_ITERS  16                 // 256*1024*16 = 4,194,304 groups >= 4M
#define N_GROUPS   (N_EDGES / 4)      // 4,000,000 int4-groups
#define BM_WORDS   (N_NODES / 32)     // 31250 u32 = 125000 B

// deterministic per-(bucket, block) cells: no global allocator at all.
// per-cell records: mean 4228, sigma 64 -> 6400 = +34 sigma (never overflows;
// clamps below guard memory safety anyway).
#define NCELL      BIN_BLOCKS
#define SLOT_CAP   6400
#define BK_BYTES   ((size_t)P_PARTS * NCELL * SLOT_CAP * 2)   // 101,580,800
#define CCNT_OFF   BK_BYTES                                   // u32[P_PARTS*NCELL]
#define OUT_BYTES_NEEDED (BK_BYTES + (size_t)P_PARTS * NCELL * 4)

// dynamic LDS layout for bin_edges
#define L_BM_BYTES   125000
#define L_BUF_BYTES  (P_PARTS * BUF_CAP * 2)   // 31744
#define L_CNT_OFF    (L_BM_BYTES + L_BUF_BYTES)
#define L_TOTAL      (L_CNT_OFF + P_PARTS * 4 * 4)   // 157,240 B <= 163,840

// ---- phase 2 ----
#define SLICES     8
#define CELLS_PER_SLICE (NCELL / SLICES)       // 32
#define HIST_WORDS 16384              // 32768 nodes, u32 per 2 nodes (c0:u8|c1:u8)

// ---- ws layout (bytes) ----
#define WS_BM_OFF      0              // u32 bitmask (131072 B reserved)
#define WS_CUR_OFF     131072         // (kept reserved; unused by fast path now)
#define WS_PART_OFF    131328         // u32[248 * 16384] slice partials (15.5 MiB)
#define WS_NEEDED      (WS_PART_OFF + (size_t)P_PARTS * SLICES * HIST_WORDS * 4)

// ---------------------------------------------------------------------------
// Phase 0: pack atom_types into a 1-bit-per-node bitmask.
// ---------------------------------------------------------------------------
__global__ __launch_bounds__(256) void pack_types(
    const int* __restrict__ types,
    unsigned*  __restrict__ bm)
{
    const int g = blockIdx.x * 256 + threadIdx.x;
    const int v = (g < N_NODES) ? types[g] : 0;
    const unsigned long long m = __ballot(v);
    if ((threadIdx.x & 31) == 0 && g < N_NODES)
        bm[g >> 5] = (unsigned)(m >> (threadIdx.x & 32));
}

// ---------------------------------------------------------------------------
// Phase 1 v5: round-2 load/bin body (44-VGPR schedule -- DO NOT hand-pipeline,
// see round-3 regression), but with the global cursor allocator DELETED.
// Each (bucket b, block) owns a fixed SLOT_CAP cell in d_out; the per-iter
// alloc phase is now a ~10-cycle LDS-only cursor bump instead of a globally
// contended atomicAdd round trip (4096 device-wide atomics per cursor word)
// that all 16 waves waited on behind barriers, 16x per block.
// ---------------------------------------------------------------------------
__global__ __launch_bounds__(BIN_THREADS, 1) void bin_edges(
    const int*      __restrict__ edge_index,   // [2, N_EDGES] int32
    const unsigned* __restrict__ bm,           // type bitmask (global)
    unsigned short* __restrict__ buckets,      // [P_PARTS][NCELL][SLOT_CAP] in d_out
    unsigned*       __restrict__ cellcnt)      // [P_PARTS][NCELL] in d_out
{
    extern __shared__ char smem[];
    unsigned* bm_lds = (unsigned*)smem;                               // 125000 B
    unsigned short (*buf)[BUF_CAP] =
        (unsigned short(*)[BUF_CAP])(smem + L_BM_BYTES);              // 31744 B
    unsigned* cnt   = (unsigned*)(smem + L_CNT_OFF);                  // [31]
    unsigned* basev = cnt + P_PARTS;
    unsigned* ccnt  = basev + P_PARTS;
    unsigned* ccur  = ccnt + P_PARTS;                                 // block-local cell cursor

    const int tid = threadIdx.x;
    for (int i = tid; i < BM_WORDS; i += BIN_THREADS) bm_lds[i] = bm[i];
    if (tid < P_PARTS) { cnt[tid] = 0u; ccur[tid] = 0u; }
    __syncthreads();

    const size_t cellbase0 = (size_t)blockIdx.x * SLOT_CAP;   // + b*NCELL*SLOT_CAP

    for (int it = 0; it < BIN_ITERS; ++it) {
        const int g = (blockIdx.x * BIN_ITERS + it) * BIN_THREADS + tid;
        if (g < N_GROUPS) {
            const int e0 = g * 4;
            const int4 s4 = *reinterpret_cast<const int4*>(edge_index + e0);
            const int4 d4 = *reinterpret_cast<const int4*>(edge_index + N_EDGES + e0);
            const int ss[4] = {s4.x, s4.y, s4.z, s4.w};
            const int dd[4] = {d4.x, d4.y, d4.z, d4.w};
#pragma unroll
            for (int k = 0; k < 4; ++k) {
                const int s = ss[k], d = dd[k];
                const unsigned ts = (bm_lds[(unsigned)s >> 5] >> (s & 31)) & 1u;
                const unsigned td = (bm_lds[(unsigned)d >> 5] >> (d & 31)) & 1u;
                {   // record for endpoint s carries d's type
                    const int b = s >> PART_BITS;
                    const unsigned short rec =
                        (unsigned short)(((s & (PART_SIZE - 1)) << 1) | td);
                    const unsigned pos = atomicAdd(&cnt[b], 1u);
                    if (pos < BUF_CAP) buf[b][pos] = rec;
                    else {  // statistically ~never: direct spill into own cell
                        const unsigned gp = atomicAdd(&ccur[b], 1u);
                        if (gp < SLOT_CAP)
                            buckets[(size_t)b * NCELL * SLOT_CAP + cellbase0 + gp] = rec;
                    }
                }
                {   // record for endpoint d carries s's type
                    const int b = d >> PART_BITS;
                    const unsigned short rec =
                        (unsigned short)(((d & (PART_SIZE - 1)) << 1) | ts);
                    const unsigned pos = atomicAdd(&cnt[b], 1u);
                    if (pos < BUF_CAP) buf[b][pos] = rec;
                    else {
                        const unsigned gp = atomicAdd(&ccur[b], 1u);
                        if (gp < SLOT_CAP)
                            buckets[(size_t)b * NCELL * SLOT_CAP + cellbase0 + gp] = rec;
                    }
                }
            }
        }
        __syncthreads();
        if (tid < P_PARTS) {   // LDS-only alloc: no global traffic, no contention
            unsigned c = cnt[tid]; if (c > BUF_CAP) c = BUF_CAP;
            unsigned bse = ccur[tid];
            if (bse > SLOT_CAP) bse = SLOT_CAP;
            if (bse + c > SLOT_CAP) c = SLOT_CAP - bse;   // memory-safety clamp
            ccur[tid] = bse + c;
            ccnt[tid] = c; basev[tid] = bse; cnt[tid] = 0u;
        }
        __syncthreads();
        // coalesced flush: wave w copies buckets 2w, 2w+1 into its own cells
        const int w = tid >> 6, lane = tid & 63;
#pragma unroll
        for (int j = 0; j < 2; ++j) {
            const int b = w * 2 + j;
            if (b < P_PARTS) {
                const unsigned c = ccnt[b];
                unsigned short* dst =
                    buckets + (size_t)b * NCELL * SLOT_CAP + cellbase0 + basev[b];
                for (unsigned e = lane; e < c; e += 64) dst[e] = buf[b][e];
            }
        }
        __syncthreads();
    }

    if (tid < P_PARTS) {
        unsigned c = ccur[tid]; if (c > SLOT_CAP) c = SLOT_CAP;
        cellcnt[tid * NCELL + blockIdx.x] = c;
    }
}

// ---------------------------------------------------------------------------
// Phase 2: per (partition, slice) block builds a 64 KB LDS histogram from its
// 32 cells (contiguous ~8.4 KB runs each; counts from cellcnt).
// ---------------------------------------------------------------------------
__global__ __launch_bounds__(512) void hist_pass(
    const unsigned short* __restrict__ buckets,
    const unsigned*       __restrict__ cellcnt,
    unsigned*             __restrict__ partials)   // [P*SLICES][HIST_WORDS]
{
    __shared__ unsigned hist[HIST_WORDS];          // exactly 64 KiB
    const int p = blockIdx.x >> 3, s = blockIdx.x & 7;
    const int tid = threadIdx.x;
    for (int i = tid; i < HIST_WORDS; i += 512) hist[i] = 0u;
    __syncthreads();

    for (int cell = s * CELLS_PER_SLICE; cell < (s + 1) * CELLS_PER_SLICE; ++cell) {
        unsigned count = cellcnt[p * NCELL + cell];
        if (count > SLOT_CAP) count = SLOT_CAP;
        const unsigned short* bk =
            buckets + ((size_t)p * NCELL + cell) * SLOT_CAP;
        const unsigned n4 = count >> 2;
        for (unsigned j = (unsigned)tid; j < n4; j += 512) {
            const ushort4 r4 = *reinterpret_cast<const ushort4*>(bk + j * 4u);
            const unsigned short rr[4] = {r4.x, r4.y, r4.z, r4.w};
#pragma unroll
            for (int k = 0; k < 4; ++k) {
                const unsigned rec = rr[k];
                const unsigned local = rec >> 1, t = rec & 1u;
                atomicAdd(&hist[local >> 1], (1u << (8u * t)) << (16u * (local & 1u)));
            }
        }
        for (unsigned i = (n4 << 2) + (unsigned)tid; i < count; i += 512) {
            const unsigned rec = bk[i];
            const unsigned local = rec >> 1, t = rec & 1u;
            atomicAdd(&hist[local >> 1], (1u << (8u * t)) << (16u * (local & 1u)));
        }
    }
    __syncthreads();
    unsigned* op = partials + (size_t)blockIdx.x * HIST_WORDS;
    for (int i = tid; i < HIST_WORDS; i += 512) op[i] = hist[i];
}

// ---------------------------------------------------------------------------
// Phase 3 (fused reduce + output) v4: per-wave coalesced staging with
// float4 global transfers. Each wave owns 64 contiguous rows = 480 float4.
// Stage-in: 8 dwordx4 loads/lane (1 KB/wave-instr) element-scattered into the
// padded LDS tile (ROW_PAD=33; 15 float4 span exactly 2 rows). Compute:
// register row (2-way bank = free), 5 dots vs W^T. Stage-out mirrors in.
// ---------------------------------------------------------------------------
#define WT_STRIDE  36
#define OT_THREADS 256
#define OT_ROWPAD  33
__global__ __launch_bounds__(OT_THREADS) void out_pass(
    const float* __restrict__ x, const float* __restrict__ Wm,
    const unsigned* __restrict__ partials,
    const unsigned* __restrict__ bm,
    float* __restrict__ out)
{
    __shared__ float sWt[D * WT_STRIDE];                    // 4320 B
    __shared__ float stg[OT_THREADS / 64][64 * OT_ROWPAD];  // 4 x 8448 B
    const int tid = threadIdx.x;
    for (int i = tid; i < D * D; i += OT_THREADS) {
        const int k = i / D, c = i - k * D;   // Wm is [k][c] row-major
        sWt[c * WT_STRIDE + k] = Wm[i];
    }

    const int wv = tid >> 6, lane = tid & 63;
    const long blockBase = (long)blockIdx.x * OT_THREADS;   // first node of block
    const long waveBase  = blockBase + (long)wv * 64;       // first node of wave
    float* ws = stg[wv];
    const long f4base = (waveBase >> 1) * 15;               // wave's first float4
    const long f4lim  = (long)N_NODES * (D / 2) / 2;        // 7,500,000 float4 total

    // ---- stage-in: 480 contiguous float4, fully coalesced ----
    const float4* gx = reinterpret_cast<const float4*>(x);
#pragma unroll
    for (int it = 0; it < 8; ++it) {
        const int g = it * 64 + lane;               // 0..511, active < 480
        if (g < 480) {
            float4 v = make_float4(0.0f, 0.0f, 0.0f, 0.0f);
            if (f4base + g < f4lim) v = gx[f4base + g];
            const int pair = g / 15, within = g - pair * 15;
            const int r0 = pair * 2, f0 = within * 4;       // f0 in [0,56]
            const float vv[4] = {v.x, v.y, v.z, v.w};
#pragma unroll
            for (int e = 0; e < 4; ++e) {
                const int ff = f0 + e;                      // float idx in 2-row pair
                const int r  = r0 + (ff >= D);
                const int c  = ff - ((ff >= D) ? D : 0);
                ws[r * OT_ROWPAD + c] = vv[e];
            }
        }
    }
    __syncthreads();   // covers sWt + cross-lane stage-in

    // ---- criterion (window start) for this node ----
    const long n = blockBase + tid;
    int start = 0;
    if (n < N_NODES) {
        const unsigned Wd   = (unsigned)(n >> 1);   // partials word = 2 nodes
        const unsigned h    = (unsigned)n & 1u;
        const unsigned p    = Wd >> 14;
        const unsigned widx = Wd & 16383u;
        const unsigned* pp  = partials + (size_t)(p * SLICES) * HIST_WORDS + widx;
        unsigned sum = 0u;
#pragma unroll
        for (int s = 0; s < SLICES; ++s) sum += pp[(size_t)s * HIST_WORDS];
        const unsigned c0 = (sum >> (16u * h)) & 0xFFu;
        const unsigned c1 = (sum >> (16u * h + 8u)) & 0xFFu;
        const unsigned t  = (bm[n >> 5] >> ((unsigned)n & 31u)) & 1u;
        const unsigned cnt    = c0 + c1;
        const unsigned same_c = t ? c1 : c0;
        const unsigned diff_c = t ? c0 : c1;
        const int mix  = diff_c ? 0 : (same_c ? (int)t + 1 : 0);
        const int crit = (cnt > DEG_THRESH ? 3 : 0) + mix;
        start = crit * WINDOW;
    }

    // ---- own row -> registers (bank = (lane+k)%32 -> 2-way = free) ----
    float xr[D];
#pragma unroll
    for (int k = 0; k < D; ++k) xr[k] = ws[lane * OT_ROWPAD + k];

    // ---- 5 dots against W^T columns ----
    float acc[WINDOW];
    const float* wc0 = &sWt[start * WT_STRIDE];
#pragma unroll
    for (int j = 0; j < WINDOW; ++j) {
        const float* wc = wc0 + j * WT_STRIDE;
        float a = 0.0f;
#pragma unroll
        for (int k = 0; k < D; ++k) a += xr[k] * wc[k];
        acc[j] = a * 0.18257418583505536f;   // 1/sqrt(30)
    }
    __syncthreads();   // all row reads done before rows are overwritten

    // ---- assemble output row in LDS (own row only) ----
    float* wr = ws + lane * OT_ROWPAD;
#pragma unroll
    for (int k = 0; k < D; ++k) wr[k] = 0.0f;
#pragma unroll
    for (int j = 0; j < WINDOW; ++j) wr[start + j] = acc[j];
    __syncthreads();   // cross-lane before coalesced store

    // ---- stage-out: 480 contiguous float4, fully coalesced ----
    float4* gout = reinterpret_cast<float4*>(out);
#pragma unroll
    for (int it = 0; it < 8; ++it) {
        const int g = it * 64 + lane;
        if (g < 480 && f4base + g < f4lim) {
            const int pair = g / 15, within = g - pair * 15;
            const int r0 = pair * 2, f0 = within * 4;
            float vv[4];
#pragma unroll
            for (int e = 0; e < 4; ++e) {
                const int ff = f0 + e;
                const int r  = r0 + (ff >= D);
                const int c  = ff - ((ff >= D) ? D : 0);
                vv[e] = ws[r * OT_ROWPAD + c];
            }
            gout[f4base + g] = make_float4(vv[0], vv[1], vv[2], vv[3]);
        }
    }
}

// ===========================================================================
// Fallback (atomic path) if buffers are unexpectedly small.
// ===========================================================================
#define SAME_INC (1u << 12)
#define DIFF_INC (1u << 22)

__global__ __launch_bounds__(256) void edge_pass_atomic(
    const int* __restrict__ edge_index, const int* __restrict__ atom_types,
    unsigned* __restrict__ agg)
{
    const int t  = blockIdx.x * blockDim.x + threadIdx.x;
    const int e0 = t * 4;
    if (e0 >= N_EDGES) return;
    const int4 s4 = *reinterpret_cast<const int4*>(edge_index + e0);
    const int4 d4 = *reinterpret_cast<const int4*>(edge_index + N_EDGES + e0);
    const int ss[4] = {s4.x, s4.y, s4.z, s4.w};
    const int dd[4] = {d4.x, d4.y, d4.z, d4.w};
#pragma unroll
    for (int k = 0; k < 4; ++k) {
        const int s = ss[k], d = dd[k];
        const unsigned add = 1u + ((atom_types[s] == atom_types[d]) ? SAME_INC : DIFF_INC);
        atomicAdd(agg + s, add);
        atomicAdd(agg + d, add);
    }
}

__global__ __launch_bounds__(256) void out_pass_agg(
    const float* __restrict__ x, const float* __restrict__ Wm,
    const unsigned* __restrict__ agg, const int* __restrict__ atom_types,
    float* __restrict__ out)
{
    __shared__ float sx[64 * D];
    __shared__ float sW[D * D];
    __shared__ int   sstart[64];
    const int tid   = threadIdx.x;
    const long base = (long)blockIdx.x * 64;
    for (int i = tid; i < D * D; i += 256) sW[i] = Wm[i];
    const float* xb = x + base * D;
    for (int i = tid; i < 64 * D; i += 256) sx[i] = xb[i];
    if (tid < 64) {
        const long n = base + tid;
        const unsigned a = agg[n];
        const int cnt = a & 0xFFFu, sc = (a >> 12) & 0x3FFu, dc = a >> 22;
        const int mix  = dc ? 0 : (sc ? atom_types[n] + 1 : 0);
        sstart[tid] = ((cnt > DEG_THRESH ? 3 : 0) + mix) * WINDOW;
    }
    __syncthreads();
    const float scale = 0.18257418583505536f;
    float* ob = out + base * D;
    for (int i = tid; i < 64 * D; i += 256) {
        const int nd = i / D, c = i - nd * D;
        float v = 0.0f;
        if ((unsigned)(c - sstart[nd]) < WINDOW) {
            float acc = 0.0f;
#pragma unroll
            for (int k = 0; k < D; ++k) acc += sx[nd * D + k] * sW[k * D + c];
            v = acc * scale;
        }
        ob[i] = v;
    }
}

// ---------------------------------------------------------------------------
extern "C" void kernel_launch(void* const* d_in, const int* in_sizes, int n_in,
                              void* d_out, int out_size, void* d_ws, size_t ws_size,
                              hipStream_t stream)
{
    const float* x          = (const float*)d_in[0];
    const float* Wm         = (const float*)d_in[1];
    const int*   edge_index = (const int*)d_in[2];
    const int*   atom_types = (const int*)d_in[3];
    float* out = (float*)d_out;

    if (ws_size >= WS_NEEDED && (size_t)out_size * 4 >= OUT_BYTES_NEEDED) {
        char* ws = (char*)d_ws;
        unsigned*       bm       = (unsigned*)(ws + WS_BM_OFF);
        unsigned*       partials = (unsigned*)(ws + WS_PART_OFF);
        unsigned short* buckets  = (unsigned short*)d_out;   // scratch, overwritten
        unsigned*       cellcnt  = (unsigned*)((char*)d_out + CCNT_OFF);

        pack_types<<<(N_NODES + 255) / 256, 256, 0, stream>>>(atom_types, bm);
        bin_edges<<<BIN_BLOCKS, BIN_THREADS, L_TOTAL, stream>>>(edge_index, bm,
                                                                buckets, cellcnt);
        hist_pass<<<P_PARTS * SLICES, 512, 0, stream>>>(buckets, cellcnt, partials);
        out_pass<<<(N_NODES + OT_THREADS - 1) / OT_THREADS, OT_THREADS, 0, stream>>>(
            x, Wm, partials, bm, out);
    } else {
        unsigned* agg = (unsigned*)d_ws;
        hipMemsetAsync(agg, 0x00, N_NODES * sizeof(unsigned), stream);
        edge_pass_atomic<<<(N_EDGES / 4) / 256, 256, 0, stream>>>(edge_index, atom_types, agg);
        out_pass_agg<<<N_NODES / 64, 256, 0, stream>>>(x, Wm, agg, atom_types, out);
    }
}

// Round 6
// 362.464 us; speedup vs baseline: 1.0573x; 1.0573x over previous
//
#include <hip/hip_runtime.h>

// Problem constants (match reference)
#define N_NODES    1000000
#define N_EDGES    16000000
#define D          30
#define WINDOW     5
#define DEG_THRESH 10

// ---- binning params ----
#define P_PARTS    31                 // partitions of 32768 nodes
#define PART_BITS  15
#define PART_SIZE  32768
#define BUF_CAP    512                // LDS staging entries per bucket
#define BIN_BLOCKS 256
#define BIN_THREADS 1024
#define BIN_ITERS  16                 // 256*1024*16 = 4,194,304 groups >= 4M
#define N_GROUPS   (N_EDGES / 4)      // 4,000,000 int4-groups
#define BM_WORDS   (N_NODES / 32)     // 31250 u32 = 125000 B

// deterministic per-(bucket, block) cells: no global allocator at all.
// per-cell records: mean 4228, sigma 64 -> 6400 = +34 sigma (never overflows;
// clamps below guard memory safety anyway).
#define NCELL      BIN_BLOCKS
#define SLOT_CAP   6400
#define BK_BYTES   ((size_t)P_PARTS * NCELL * SLOT_CAP * 2)   // 101,580,800
#define CCNT_OFF   BK_BYTES                                   // u32[P_PARTS*NCELL]
#define OUT_BYTES_NEEDED (BK_BYTES + (size_t)P_PARTS * NCELL * 4)

// dynamic LDS layout for bin_edges
#define L_BM_BYTES   125000
#define L_BUF_BYTES  (P_PARTS * BUF_CAP * 2)   // 31744
#define L_CNT_OFF    (L_BM_BYTES + L_BUF_BYTES)
#define L_TOTAL      (L_CNT_OFF + P_PARTS * 4 * 4)   // 157,240 B <= 163,840

// ---- phase 2 ----
#define SLICES     8
#define CELLS_PER_SLICE (NCELL / SLICES)       // 32
#define HIST_WORDS 16384              // 32768 nodes, u32 per 2 nodes (c0:u8|c1:u8)

// ---- ws layout (bytes) ----
#define WS_BM_OFF      0              // u32 bitmask (131072 B reserved)
#define WS_CUR_OFF     131072         // (kept reserved; unused by fast path now)
#define WS_PART_OFF    131328         // u32[248 * 16384] slice partials (15.5 MiB)
#define WS_NEEDED      (WS_PART_OFF + (size_t)P_PARTS * SLICES * HIST_WORDS * 4)

// ---------------------------------------------------------------------------
// Phase 0: pack atom_types into a 1-bit-per-node bitmask.
// ---------------------------------------------------------------------------
__global__ __launch_bounds__(256) void pack_types(
    const int* __restrict__ types,
    unsigned*  __restrict__ bm)
{
    const int g = blockIdx.x * 256 + threadIdx.x;
    const int v = (g < N_NODES) ? types[g] : 0;
    const unsigned long long m = __ballot(v);
    if ((threadIdx.x & 31) == 0 && g < N_NODES)
        bm[g >> 5] = (unsigned)(m >> (threadIdx.x & 32));
}

// ---------------------------------------------------------------------------
// Phase 1 v5 (UNCHANGED from round 5 -- verified 80.5 us): round-2 load/bin
// body (44->28 VGPR schedule; DO NOT hand-pipeline, see round-3 regression),
// deterministic per-(bucket, block) cells, LDS-only cursor alloc.
// ---------------------------------------------------------------------------
__global__ __launch_bounds__(BIN_THREADS, 1) void bin_edges(
    const int*      __restrict__ edge_index,   // [2, N_EDGES] int32
    const unsigned* __restrict__ bm,           // type bitmask (global)
    unsigned short* __restrict__ buckets,      // [P_PARTS][NCELL][SLOT_CAP] in d_out
    unsigned*       __restrict__ cellcnt)      // [P_PARTS][NCELL] in d_out
{
    extern __shared__ char smem[];
    unsigned* bm_lds = (unsigned*)smem;                               // 125000 B
    unsigned short (*buf)[BUF_CAP] =
        (unsigned short(*)[BUF_CAP])(smem + L_BM_BYTES);              // 31744 B
    unsigned* cnt   = (unsigned*)(smem + L_CNT_OFF);                  // [31]
    unsigned* basev = cnt + P_PARTS;
    unsigned* ccnt  = basev + P_PARTS;
    unsigned* ccur  = ccnt + P_PARTS;                                 // block-local cell cursor

    const int tid = threadIdx.x;
    for (int i = tid; i < BM_WORDS; i += BIN_THREADS) bm_lds[i] = bm[i];
    if (tid < P_PARTS) { cnt[tid] = 0u; ccur[tid] = 0u; }
    __syncthreads();

    const size_t cellbase0 = (size_t)blockIdx.x * SLOT_CAP;   // + b*NCELL*SLOT_CAP

    for (int it = 0; it < BIN_ITERS; ++it) {
        const int g = (blockIdx.x * BIN_ITERS + it) * BIN_THREADS + tid;
        if (g < N_GROUPS) {
            const int e0 = g * 4;
            const int4 s4 = *reinterpret_cast<const int4*>(edge_index + e0);
            const int4 d4 = *reinterpret_cast<const int4*>(edge_index + N_EDGES + e0);
            const int ss[4] = {s4.x, s4.y, s4.z, s4.w};
            const int dd[4] = {d4.x, d4.y, d4.z, d4.w};
#pragma unroll
            for (int k = 0; k < 4; ++k) {
                const int s = ss[k], d = dd[k];
                const unsigned ts = (bm_lds[(unsigned)s >> 5] >> (s & 31)) & 1u;
                const unsigned td = (bm_lds[(unsigned)d >> 5] >> (d & 31)) & 1u;
                {   // record for endpoint s carries d's type
                    const int b = s >> PART_BITS;
                    const unsigned short rec =
                        (unsigned short)(((s & (PART_SIZE - 1)) << 1) | td);
                    const unsigned pos = atomicAdd(&cnt[b], 1u);
                    if (pos < BUF_CAP) buf[b][pos] = rec;
                    else {  // statistically ~never: direct spill into own cell
                        const unsigned gp = atomicAdd(&ccur[b], 1u);
                        if (gp < SLOT_CAP)
                            buckets[(size_t)b * NCELL * SLOT_CAP + cellbase0 + gp] = rec;
                    }
                }
                {   // record for endpoint d carries s's type
                    const int b = d >> PART_BITS;
                    const unsigned short rec =
                        (unsigned short)(((d & (PART_SIZE - 1)) << 1) | ts);
                    const unsigned pos = atomicAdd(&cnt[b], 1u);
                    if (pos < BUF_CAP) buf[b][pos] = rec;
                    else {
                        const unsigned gp = atomicAdd(&ccur[b], 1u);
                        if (gp < SLOT_CAP)
                            buckets[(size_t)b * NCELL * SLOT_CAP + cellbase0 + gp] = rec;
                    }
                }
            }
        }
        __syncthreads();
        if (tid < P_PARTS) {   // LDS-only alloc: no global traffic, no contention
            unsigned c = cnt[tid]; if (c > BUF_CAP) c = BUF_CAP;
            unsigned bse = ccur[tid];
            if (bse > SLOT_CAP) bse = SLOT_CAP;
            if (bse + c > SLOT_CAP) c = SLOT_CAP - bse;   // memory-safety clamp
            ccur[tid] = bse + c;
            ccnt[tid] = c; basev[tid] = bse; cnt[tid] = 0u;
        }
        __syncthreads();
        // coalesced flush: wave w copies buckets 2w, 2w+1 into its own cells
        const int w = tid >> 6, lane = tid & 63;
#pragma unroll
        for (int j = 0; j < 2; ++j) {
            const int b = w * 2 + j;
            if (b < P_PARTS) {
                const unsigned c = ccnt[b];
                unsigned short* dst =
                    buckets + (size_t)b * NCELL * SLOT_CAP + cellbase0 + basev[b];
                for (unsigned e = lane; e < c; e += 64) dst[e] = buf[b][e];
            }
        }
        __syncthreads();
    }

    if (tid < P_PARTS) {
        unsigned c = ccur[tid]; if (c > SLOT_CAP) c = SLOT_CAP;
        cellcnt[tid * NCELL + blockIdx.x] = c;
    }
}

// ---------------------------------------------------------------------------
// Phase 2 v2: round-5's version serialized on 32 sequential cells, each gated
// by a dependent cellcnt load (~200-900cy) with 1 block/CU -> ~+14us. Now:
// all 32 cell counts preloaded once (coalesced, tid<32); 8 waves each own 4
// cells independently (MLP across waves, no block-wide serial walk); uint4
// record loads (16B/lane = 1KB/wave-instr, 8 records); uint4 LDS init and
// partials copy-out. Histogram atomics unchanged (never the bottleneck).
// ---------------------------------------------------------------------------
__global__ __launch_bounds__(512) void hist_pass(
    const unsigned short* __restrict__ buckets,
    const unsigned*       __restrict__ cellcnt,
    unsigned*             __restrict__ partials)   // [P*SLICES][HIST_WORDS]
{
    __shared__ unsigned hist[HIST_WORDS];          // exactly 64 KiB
    __shared__ unsigned scnt[CELLS_PER_SLICE];
    const int p = blockIdx.x >> 3, s = blockIdx.x & 7;
    const int tid = threadIdx.x;

    uint4* h4 = reinterpret_cast<uint4*>(hist);
    for (int i = tid; i < HIST_WORDS / 4; i += 512)
        h4[i] = make_uint4(0u, 0u, 0u, 0u);
    if (tid < CELLS_PER_SLICE) {
        unsigned c = cellcnt[p * NCELL + s * CELLS_PER_SLICE + tid];
        scnt[tid] = (c > SLOT_CAP) ? SLOT_CAP : c;
    }
    __syncthreads();

    const int wv = tid >> 6, lane = tid & 63;
#pragma unroll
    for (int cc = 0; cc < CELLS_PER_SLICE / 8; ++cc) {   // 8 waves x 4 cells
        const int cl = wv * (CELLS_PER_SLICE / 8) + cc;  // local cell 0..31
        const unsigned count = scnt[cl];
        const unsigned short* bk =
            buckets + ((size_t)p * NCELL + s * CELLS_PER_SLICE + cl) * SLOT_CAP;
        const unsigned n8 = count >> 3;                  // uint4 = 8 records
        for (unsigned j = (unsigned)lane; j < n8; j += 64) {
            const uint4 q = *reinterpret_cast<const uint4*>(bk + j * 8u);
            const unsigned ww[4] = {q.x, q.y, q.z, q.w};
#pragma unroll
            for (int k = 0; k < 4; ++k) {
                const unsigned r0 = ww[k] & 0xFFFFu, r1 = ww[k] >> 16;
                unsigned local = r0 >> 1, t = r0 & 1u;
                atomicAdd(&hist[local >> 1], (1u << (8u * t)) << (16u * (local & 1u)));
                local = r1 >> 1; t = r1 & 1u;
                atomicAdd(&hist[local >> 1], (1u << (8u * t)) << (16u * (local & 1u)));
            }
        }
        for (unsigned i = (n8 << 3) + (unsigned)lane; i < count; i += 64) {
            const unsigned rec = bk[i];
            const unsigned local = rec >> 1, t = rec & 1u;
            atomicAdd(&hist[local >> 1], (1u << (8u * t)) << (16u * (local & 1u)));
        }
    }
    __syncthreads();
    uint4* op4 = reinterpret_cast<uint4*>(partials + (size_t)blockIdx.x * HIST_WORDS);
    for (int i = tid; i < HIST_WORDS / 4; i += 512) op4[i] = h4[i];
}

// ---------------------------------------------------------------------------
// Phase 3 (fused reduce + output) v4 (UNCHANGED): per-wave coalesced staging
// with float4 global transfers; padded LDS tile (ROW_PAD=33); register row,
// 5 dots vs W^T.
// ---------------------------------------------------------------------------
#define WT_STRIDE  36
#define OT_THREADS 256
#define OT_ROWPAD  33
__global__ __launch_bounds__(OT_THREADS) void out_pass(
    const float* __restrict__ x, const float* __restrict__ Wm,
    const unsigned* __restrict__ partials,
    const unsigned* __restrict__ bm,
    float* __restrict__ out)
{
    __shared__ float sWt[D * WT_STRIDE];                    // 4320 B
    __shared__ float stg[OT_THREADS / 64][64 * OT_ROWPAD];  // 4 x 8448 B
    const int tid = threadIdx.x;
    for (int i = tid; i < D * D; i += OT_THREADS) {
        const int k = i / D, c = i - k * D;   // Wm is [k][c] row-major
        sWt[c * WT_STRIDE + k] = Wm[i];
    }

    const int wv = tid >> 6, lane = tid & 63;
    const long blockBase = (long)blockIdx.x * OT_THREADS;   // first node of block
    const long waveBase  = blockBase + (long)wv * 64;       // first node of wave
    float* ws = stg[wv];
    const long f4base = (waveBase >> 1) * 15;               // wave's first float4
    const long f4lim  = (long)N_NODES * (D / 2) / 2;        // 7,500,000 float4 total

    // ---- stage-in: 480 contiguous float4, fully coalesced ----
    const float4* gx = reinterpret_cast<const float4*>(x);
#pragma unroll
    for (int it = 0; it < 8; ++it) {
        const int g = it * 64 + lane;               // 0..511, active < 480
        if (g < 480) {
            float4 v = make_float4(0.0f, 0.0f, 0.0f, 0.0f);
            if (f4base + g < f4lim) v = gx[f4base + g];
            const int pair = g / 15, within = g - pair * 15;
            const int r0 = pair * 2, f0 = within * 4;       // f0 in [0,56]
            const float vv[4] = {v.x, v.y, v.z, v.w};
#pragma unroll
            for (int e = 0; e < 4; ++e) {
                const int ff = f0 + e;                      // float idx in 2-row pair
                const int r  = r0 + (ff >= D);
                const int c  = ff - ((ff >= D) ? D : 0);
                ws[r * OT_ROWPAD + c] = vv[e];
            }
        }
    }
    __syncthreads();   // covers sWt + cross-lane stage-in

    // ---- criterion (window start) for this node ----
    const long n = blockBase + tid;
    int start = 0;
    if (n < N_NODES) {
        const unsigned Wd   = (unsigned)(n >> 1);   // partials word = 2 nodes
        const unsigned h    = (unsigned)n & 1u;
        const unsigned p    = Wd >> 14;
        const unsigned widx = Wd & 16383u;
        const unsigned* pp  = partials + (size_t)(p * SLICES) * HIST_WORDS + widx;
        unsigned sum = 0u;
#pragma unroll
        for (int s = 0; s < SLICES; ++s) sum += pp[(size_t)s * HIST_WORDS];
        const unsigned c0 = (sum >> (16u * h)) & 0xFFu;
        const unsigned c1 = (sum >> (16u * h + 8u)) & 0xFFu;
        const unsigned t  = (bm[n >> 5] >> ((unsigned)n & 31u)) & 1u;
        const unsigned cnt    = c0 + c1;
        const unsigned same_c = t ? c1 : c0;
        const unsigned diff_c = t ? c0 : c1;
        const int mix  = diff_c ? 0 : (same_c ? (int)t + 1 : 0);
        const int crit = (cnt > DEG_THRESH ? 3 : 0) + mix;
        start = crit * WINDOW;
    }

    // ---- own row -> registers (bank = (lane+k)%32 -> 2-way = free) ----
    float xr[D];
#pragma unroll
    for (int k = 0; k < D; ++k) xr[k] = ws[lane * OT_ROWPAD + k];

    // ---- 5 dots against W^T columns ----
    float acc[WINDOW];
    const float* wc0 = &sWt[start * WT_STRIDE];
#pragma unroll
    for (int j = 0; j < WINDOW; ++j) {
        const float* wc = wc0 + j * WT_STRIDE;
        float a = 0.0f;
#pragma unroll
        for (int k = 0; k < D; ++k) a += xr[k] * wc[k];
        acc[j] = a * 0.18257418583505536f;   // 1/sqrt(30)
    }
    __syncthreads();   // all row reads done before rows are overwritten

    // ---- assemble output row in LDS (own row only) ----
    float* wr = ws + lane * OT_ROWPAD;
#pragma unroll
    for (int k = 0; k < D; ++k) wr[k] = 0.0f;
#pragma unroll
    for (int j = 0; j < WINDOW; ++j) wr[start + j] = acc[j];
    __syncthreads();   // cross-lane before coalesced store

    // ---- stage-out: 480 contiguous float4, fully coalesced ----
    float4* gout = reinterpret_cast<float4*>(out);
#pragma unroll
    for (int it = 0; it < 8; ++it) {
        const int g = it * 64 + lane;
        if (g < 480 && f4base + g < f4lim) {
            const int pair = g / 15, within = g - pair * 15;
            const int r0 = pair * 2, f0 = within * 4;
            float vv[4];
#pragma unroll
            for (int e = 0; e < 4; ++e) {
                const int ff = f0 + e;
                const int r  = r0 + (ff >= D);
                const int c  = ff - ((ff >= D) ? D : 0);
                vv[e] = ws[r * OT_ROWPAD + c];
            }
            gout[f4base + g] = make_float4(vv[0], vv[1], vv[2], vv[3]);
        }
    }
}

// ===========================================================================
// Fallback (atomic path) if buffers are unexpectedly small.
// ===========================================================================
#define SAME_INC (1u << 12)
#define DIFF_INC (1u << 22)

__global__ __launch_bounds__(256) void edge_pass_atomic(
    const int* __restrict__ edge_index, const int* __restrict__ atom_types,
    unsigned* __restrict__ agg)
{
    const int t  = blockIdx.x * blockDim.x + threadIdx.x;
    const int e0 = t * 4;
    if (e0 >= N_EDGES) return;
    const int4 s4 = *reinterpret_cast<const int4*>(edge_index + e0);
    const int4 d4 = *reinterpret_cast<const int4*>(edge_index + N_EDGES + e0);
    const int ss[4] = {s4.x, s4.y, s4.z, s4.w};
    const int dd[4] = {d4.x, d4.y, d4.z, d4.w};
#pragma unroll
    for (int k = 0; k < 4; ++k) {
        const int s = ss[k], d = dd[k];
        const unsigned add = 1u + ((atom_types[s] == atom_types[d]) ? SAME_INC : DIFF_INC);
        atomicAdd(agg + s, add);
        atomicAdd(agg + d, add);
    }
}

__global__ __launch_bounds__(256) void out_pass_agg(
    const float* __restrict__ x, const float* __restrict__ Wm,
    const unsigned* __restrict__ agg, const int* __restrict__ atom_types,
    float* __restrict__ out)
{
    __shared__ float sx[64 * D];
    __shared__ float sW[D * D];
    __shared__ int   sstart[64];
    const int tid   = threadIdx.x;
    const long base = (long)blockIdx.x * 64;
    for (int i = tid; i < D * D; i += 256) sW[i] = Wm[i];
    const float* xb = x + base * D;
    for (int i = tid; i < 64 * D; i += 256) sx[i] = xb[i];
    if (tid < 64) {
        const long n = base + tid;
        const unsigned a = agg[n];
        const int cnt = a & 0xFFFu, sc = (a >> 12) & 0x3FFu, dc = a >> 22;
        const int mix  = dc ? 0 : (sc ? atom_types[n] + 1 : 0);
        sstart[tid] = ((cnt > DEG_THRESH ? 3 : 0) + mix) * WINDOW;
    }
    __syncthreads();
    const float scale = 0.18257418583505536f;
    float* ob = out + base * D;
    for (int i = tid; i < 64 * D; i += 256) {
        const int nd = i / D, c = i - nd * D;
        float v = 0.0f;
        if ((unsigned)(c - sstart[nd]) < WINDOW) {
            float acc = 0.0f;
#pragma unroll
            for (int k = 0; k < D; ++k) acc += sx[nd * D + k] * sW[k * D + c];
            v = acc * scale;
        }
        ob[i] = v;
    }
}

// ---------------------------------------------------------------------------
extern "C" void kernel_launch(void* const* d_in, const int* in_sizes, int n_in,
                              void* d_out, int out_size, void* d_ws, size_t ws_size,
                              hipStream_t stream)
{
    const float* x          = (const float*)d_in[0];
    const float* Wm         = (const float*)d_in[1];
    const int*   edge_index = (const int*)d_in[2];
    const int*   atom_types = (const int*)d_in[3];
    float* out = (float*)d_out;

    if (ws_size >= WS_NEEDED && (size_t)out_size * 4 >= OUT_BYTES_NEEDED) {
        char* ws = (char*)d_ws;
        unsigned*       bm       = (unsigned*)(ws + WS_BM_OFF);
        unsigned*       partials = (unsigned*)(ws + WS_PART_OFF);
        unsigned short* buckets  = (unsigned short*)d_out;   // scratch, overwritten
        unsigned*       cellcnt  = (unsigned*)((char*)d_out + CCNT_OFF);

        pack_types<<<(N_NODES + 255) / 256, 256, 0, stream>>>(atom_types, bm);
        bin_edges<<<BIN_BLOCKS, BIN_THREADS, L_TOTAL, stream>>>(edge_index, bm,
                                                                buckets, cellcnt);
        hist_pass<<<P_PARTS * SLICES, 512, 0, stream>>>(buckets, cellcnt, partials);
        out_pass<<<(N_NODES + OT_THREADS - 1) / OT_THREADS, OT_THREADS, 0, stream>>>(
            x, Wm, partials, bm, out);
    } else {
        unsigned* agg = (unsigned*)d_ws;
        hipMemsetAsync(agg, 0x00, N_NODES * sizeof(unsigned), stream);
        edge_pass_atomic<<<(N_EDGES / 4) / 256, 256, 0, stream>>>(edge_index, atom_types, agg);
        out_pass_agg<<<N_NODES / 64, 256, 0, stream>>>(x, Wm, agg, atom_types, out);
    }
}

// Round 7
// 360.215 us; speedup vs baseline: 1.0639x; 1.0062x over previous
//
#include <hip/hip_runtime.h>

// Problem constants (match reference)
#define N_NODES    1000000
#define N_EDGES    16000000
#define D          30
#define WINDOW     5
#define DEG_THRESH 10

// ---- binning params ----
#define P_PARTS    31                 // partitions of 32768 nodes
#define PART_BITS  15
#define PART_SIZE  32768
#define BUF_CAP    616                // staging entries/bucket (2-iter fill 528 +3.8sigma)
#define BIN_BLOCKS 256
#define BIN_THREADS 1024
#define BIN_ITERS  16                 // 256*1024*16 = 4,194,304 groups >= 4M
#define N_GROUPS   (N_EDGES / 4)      // 4,000,000 int4-groups
#define BM_WORDS   (N_NODES / 32)     // 31250 u32 = 125000 B

// deterministic per-(bucket, block) cells: no global allocator at all.
// per-cell records: mean 4228, sigma 64 -> 6400 = +34 sigma (never overflows;
// clamps below guard memory safety anyway).
#define NCELL      BIN_BLOCKS
#define SLOT_CAP   6400
#define BK_BYTES   ((size_t)P_PARTS * NCELL * SLOT_CAP * 2)   // 101,580,800
#define CCNT_OFF   BK_BYTES                                   // u32[P_PARTS*NCELL]
#define OUT_BYTES_NEEDED (BK_BYTES + (size_t)P_PARTS * NCELL * 4)

// dynamic LDS layout for bin_edges
#define L_BM_BYTES   125000
#define L_BUF_BYTES  (P_PARTS * BUF_CAP * 2)   // 38192
#define L_CNT_OFF    (L_BM_BYTES + L_BUF_BYTES)
#define L_TOTAL      (L_CNT_OFF + P_PARTS * 4 * 4)   // 163,688 B <= 163,840

// ---- phase 2 ----
#define SLICES     8
#define CELLS_PER_SLICE (NCELL / SLICES)       // 32
#define HIST_WORDS 16384              // 32768 nodes, u32 per 2 nodes (c0:u8|c1:u8)

// ---- ws layout (bytes) ----
#define WS_BM_OFF      0              // u32 bitmask (131072 B reserved)
#define WS_CUR_OFF     131072         // (kept reserved; unused by fast path now)
#define WS_PART_OFF    131328         // u32[248 * 16384] slice partials (15.5 MiB)
#define WS_NEEDED      (WS_PART_OFF + (size_t)P_PARTS * SLICES * HIST_WORDS * 4)

// ---------------------------------------------------------------------------
// Phase 0: pack atom_types into a 1-bit-per-node bitmask.
// ---------------------------------------------------------------------------
__global__ __launch_bounds__(256) void pack_types(
    const int* __restrict__ types,
    unsigned*  __restrict__ bm)
{
    const int g = blockIdx.x * 256 + threadIdx.x;
    const int v = (g < N_NODES) ? types[g] : 0;
    const unsigned long long m = __ballot(v);
    if ((threadIdx.x & 31) == 0 && g < N_NODES)
        bm[g >> 5] = (unsigned)(m >> (threadIdx.x & 32));
}

// ---------------------------------------------------------------------------
// Phase 1 v6: identical load/bin body (DO NOT hand-pipeline -- round-3
// regression: explicit prefetch collapsed VGPR 44->32 and sank loads to
// uses), deterministic per-(bucket, block) cells, LDS-only cursor alloc.
// NEW vs v5 (isolated change): flush every 2 iterations (BUF_CAP 512->616).
// Barriers 48 -> 24; flush runs 2x longer (c~528, better tail amortization);
// no barrier needed between the two bin iterations of a period (staging is
// atomic-cursor based; spill-path ccur atomics only race other spills, and
// the alloc read is barrier-separated).
// ---------------------------------------------------------------------------
__global__ __launch_bounds__(BIN_THREADS, 1) void bin_edges(
    const int*      __restrict__ edge_index,   // [2, N_EDGES] int32
    const unsigned* __restrict__ bm,           // type bitmask (global)
    unsigned short* __restrict__ buckets,      // [P_PARTS][NCELL][SLOT_CAP] in d_out
    unsigned*       __restrict__ cellcnt)      // [P_PARTS][NCELL] in d_out
{
    extern __shared__ char smem[];
    unsigned* bm_lds = (unsigned*)smem;                               // 125000 B
    unsigned short (*buf)[BUF_CAP] =
        (unsigned short(*)[BUF_CAP])(smem + L_BM_BYTES);              // 38192 B
    unsigned* cnt   = (unsigned*)(smem + L_CNT_OFF);                  // [31]
    unsigned* basev = cnt + P_PARTS;
    unsigned* ccnt  = basev + P_PARTS;
    unsigned* ccur  = ccnt + P_PARTS;                                 // block-local cell cursor

    const int tid = threadIdx.x;
    for (int i = tid; i < BM_WORDS; i += BIN_THREADS) bm_lds[i] = bm[i];
    if (tid < P_PARTS) { cnt[tid] = 0u; ccur[tid] = 0u; }
    __syncthreads();

    const size_t cellbase0 = (size_t)blockIdx.x * SLOT_CAP;   // + b*NCELL*SLOT_CAP

    for (int it = 0; it < BIN_ITERS; ++it) {
        const int g = (blockIdx.x * BIN_ITERS + it) * BIN_THREADS + tid;
        if (g < N_GROUPS) {
            const int e0 = g * 4;
            const int4 s4 = *reinterpret_cast<const int4*>(edge_index + e0);
            const int4 d4 = *reinterpret_cast<const int4*>(edge_index + N_EDGES + e0);
            const int ss[4] = {s4.x, s4.y, s4.z, s4.w};
            const int dd[4] = {d4.x, d4.y, d4.z, d4.w};
#pragma unroll
            for (int k = 0; k < 4; ++k) {
                const int s = ss[k], d = dd[k];
                const unsigned ts = (bm_lds[(unsigned)s >> 5] >> (s & 31)) & 1u;
                const unsigned td = (bm_lds[(unsigned)d >> 5] >> (d & 31)) & 1u;
                {   // record for endpoint s carries d's type
                    const int b = s >> PART_BITS;
                    const unsigned short rec =
                        (unsigned short)(((s & (PART_SIZE - 1)) << 1) | td);
                    const unsigned pos = atomicAdd(&cnt[b], 1u);
                    if (pos < BUF_CAP) buf[b][pos] = rec;
                    else {  // statistically ~never: direct spill into own cell
                        const unsigned gp = atomicAdd(&ccur[b], 1u);
                        if (gp < SLOT_CAP)
                            buckets[(size_t)b * NCELL * SLOT_CAP + cellbase0 + gp] = rec;
                    }
                }
                {   // record for endpoint d carries s's type
                    const int b = d >> PART_BITS;
                    const unsigned short rec =
                        (unsigned short)(((d & (PART_SIZE - 1)) << 1) | ts);
                    const unsigned pos = atomicAdd(&cnt[b], 1u);
                    if (pos < BUF_CAP) buf[b][pos] = rec;
                    else {
                        const unsigned gp = atomicAdd(&ccur[b], 1u);
                        if (gp < SLOT_CAP)
                            buckets[(size_t)b * NCELL * SLOT_CAP + cellbase0 + gp] = rec;
                    }
                }
            }
        }

        // ---- flush every 2 iterations ----
        if ((it & 1) == 1) {
            __syncthreads();   // all records of this period staged
            if (tid < P_PARTS) {   // LDS-only alloc: no global traffic
                unsigned c = cnt[tid]; if (c > BUF_CAP) c = BUF_CAP;
                unsigned bse = ccur[tid];
                if (bse > SLOT_CAP) bse = SLOT_CAP;
                if (bse + c > SLOT_CAP) c = SLOT_CAP - bse;   // memory-safety clamp
                ccur[tid] = bse + c;
                ccnt[tid] = c; basev[tid] = bse; cnt[tid] = 0u;
            }
            __syncthreads();
            // coalesced flush: wave w copies buckets 2w, 2w+1 into its own cells
            const int w = tid >> 6, lane = tid & 63;
#pragma unroll
            for (int j = 0; j < 2; ++j) {
                const int b = w * 2 + j;
                if (b < P_PARTS) {
                    const unsigned c = ccnt[b];
                    unsigned short* dst =
                        buckets + (size_t)b * NCELL * SLOT_CAP + cellbase0 + basev[b];
                    for (unsigned e = lane; e < c; e += 64) dst[e] = buf[b][e];
                }
            }
            __syncthreads();   // buffers reusable
        }
    }

    if (tid < P_PARTS) {
        unsigned c = ccur[tid]; if (c > SLOT_CAP) c = SLOT_CAP;
        cellcnt[tid * NCELL + blockIdx.x] = c;
    }
}

// ---------------------------------------------------------------------------
// Phase 2 v2 (UNCHANGED from round 6 -- verified): counts preloaded once;
// 8 waves x 4 cells independently; uint4 record loads; uint4 init/copy-out.
// ---------------------------------------------------------------------------
__global__ __launch_bounds__(512) void hist_pass(
    const unsigned short* __restrict__ buckets,
    const unsigned*       __restrict__ cellcnt,
    unsigned*             __restrict__ partials)   // [P*SLICES][HIST_WORDS]
{
    __shared__ unsigned hist[HIST_WORDS];          // exactly 64 KiB
    __shared__ unsigned scnt[CELLS_PER_SLICE];
    const int p = blockIdx.x >> 3, s = blockIdx.x & 7;
    const int tid = threadIdx.x;

    uint4* h4 = reinterpret_cast<uint4*>(hist);
    for (int i = tid; i < HIST_WORDS / 4; i += 512)
        h4[i] = make_uint4(0u, 0u, 0u, 0u);
    if (tid < CELLS_PER_SLICE) {
        unsigned c = cellcnt[p * NCELL + s * CELLS_PER_SLICE + tid];
        scnt[tid] = (c > SLOT_CAP) ? SLOT_CAP : c;
    }
    __syncthreads();

    const int wv = tid >> 6, lane = tid & 63;
#pragma unroll
    for (int cc = 0; cc < CELLS_PER_SLICE / 8; ++cc) {   // 8 waves x 4 cells
        const int cl = wv * (CELLS_PER_SLICE / 8) + cc;  // local cell 0..31
        const unsigned count = scnt[cl];
        const unsigned short* bk =
            buckets + ((size_t)p * NCELL + s * CELLS_PER_SLICE + cl) * SLOT_CAP;
        const unsigned n8 = count >> 3;                  // uint4 = 8 records
        for (unsigned j = (unsigned)lane; j < n8; j += 64) {
            const uint4 q = *reinterpret_cast<const uint4*>(bk + j * 8u);
            const unsigned ww[4] = {q.x, q.y, q.z, q.w};
#pragma unroll
            for (int k = 0; k < 4; ++k) {
                const unsigned r0 = ww[k] & 0xFFFFu, r1 = ww[k] >> 16;
                unsigned local = r0 >> 1, t = r0 & 1u;
                atomicAdd(&hist[local >> 1], (1u << (8u * t)) << (16u * (local & 1u)));
                local = r1 >> 1; t = r1 & 1u;
                atomicAdd(&hist[local >> 1], (1u << (8u * t)) << (16u * (local & 1u)));
            }
        }
        for (unsigned i = (n8 << 3) + (unsigned)lane; i < count; i += 64) {
            const unsigned rec = bk[i];
            const unsigned local = rec >> 1, t = rec & 1u;
            atomicAdd(&hist[local >> 1], (1u << (8u * t)) << (16u * (local & 1u)));
        }
    }
    __syncthreads();
    uint4* op4 = reinterpret_cast<uint4*>(partials + (size_t)blockIdx.x * HIST_WORDS);
    for (int i = tid; i < HIST_WORDS / 4; i += 512) op4[i] = h4[i];
}

// ---------------------------------------------------------------------------
// Phase 3 (fused reduce + output) v4 (UNCHANGED): per-wave coalesced staging
// with float4 global transfers; padded LDS tile (ROW_PAD=33); register row,
// 5 dots vs W^T.
// ---------------------------------------------------------------------------
#define WT_STRIDE  36
#define OT_THREADS 256
#define OT_ROWPAD  33
__global__ __launch_bounds__(OT_THREADS) void out_pass(
    const float* __restrict__ x, const float* __restrict__ Wm,
    const unsigned* __restrict__ partials,
    const unsigned* __restrict__ bm,
    float* __restrict__ out)
{
    __shared__ float sWt[D * WT_STRIDE];                    // 4320 B
    __shared__ float stg[OT_THREADS / 64][64 * OT_ROWPAD];  // 4 x 8448 B
    const int tid = threadIdx.x;
    for (int i = tid; i < D * D; i += OT_THREADS) {
        const int k = i / D, c = i - k * D;   // Wm is [k][c] row-major
        sWt[c * WT_STRIDE + k] = Wm[i];
    }

    const int wv = tid >> 6, lane = tid & 63;
    const long blockBase = (long)blockIdx.x * OT_THREADS;   // first node of block
    const long waveBase  = blockBase + (long)wv * 64;       // first node of wave
    float* ws = stg[wv];
    const long f4base = (waveBase >> 1) * 15;               // wave's first float4
    const long f4lim  = (long)N_NODES * (D / 2) / 2;        // 7,500,000 float4 total

    // ---- stage-in: 480 contiguous float4, fully coalesced ----
    const float4* gx = reinterpret_cast<const float4*>(x);
#pragma unroll
    for (int it = 0; it < 8; ++it) {
        const int g = it * 64 + lane;               // 0..511, active < 480
        if (g < 480) {
            float4 v = make_float4(0.0f, 0.0f, 0.0f, 0.0f);
            if (f4base + g < f4lim) v = gx[f4base + g];
            const int pair = g / 15, within = g - pair * 15;
            const int r0 = pair * 2, f0 = within * 4;       // f0 in [0,56]
            const float vv[4] = {v.x, v.y, v.z, v.w};
#pragma unroll
            for (int e = 0; e < 4; ++e) {
                const int ff = f0 + e;                      // float idx in 2-row pair
                const int r  = r0 + (ff >= D);
                const int c  = ff - ((ff >= D) ? D : 0);
                ws[r * OT_ROWPAD + c] = vv[e];
            }
        }
    }
    __syncthreads();   // covers sWt + cross-lane stage-in

    // ---- criterion (window start) for this node ----
    const long n = blockBase + tid;
    int start = 0;
    if (n < N_NODES) {
        const unsigned Wd   = (unsigned)(n >> 1);   // partials word = 2 nodes
        const unsigned h    = (unsigned)n & 1u;
        const unsigned p    = Wd >> 14;
        const unsigned widx = Wd & 16383u;
        const unsigned* pp  = partials + (size_t)(p * SLICES) * HIST_WORDS + widx;
        unsigned sum = 0u;
#pragma unroll
        for (int s = 0; s < SLICES; ++s) sum += pp[(size_t)s * HIST_WORDS];
        const unsigned c0 = (sum >> (16u * h)) & 0xFFu;
        const unsigned c1 = (sum >> (16u * h + 8u)) & 0xFFu;
        const unsigned t  = (bm[n >> 5] >> ((unsigned)n & 31u)) & 1u;
        const unsigned cnt    = c0 + c1;
        const unsigned same_c = t ? c1 : c0;
        const unsigned diff_c = t ? c0 : c1;
        const int mix  = diff_c ? 0 : (same_c ? (int)t + 1 : 0);
        const int crit = (cnt > DEG_THRESH ? 3 : 0) + mix;
        start = crit * WINDOW;
    }

    // ---- own row -> registers (bank = (lane+k)%32 -> 2-way = free) ----
    float xr[D];
#pragma unroll
    for (int k = 0; k < D; ++k) xr[k] = ws[lane * OT_ROWPAD + k];

    // ---- 5 dots against W^T columns ----
    float acc[WINDOW];
    const float* wc0 = &sWt[start * WT_STRIDE];
#pragma unroll
    for (int j = 0; j < WINDOW; ++j) {
        const float* wc = wc0 + j * WT_STRIDE;
        float a = 0.0f;
#pragma unroll
        for (int k = 0; k < D; ++k) a += xr[k] * wc[k];
        acc[j] = a * 0.18257418583505536f;   // 1/sqrt(30)
    }
    __syncthreads();   // all row reads done before rows are overwritten

    // ---- assemble output row in LDS (own row only) ----
    float* wr = ws + lane * OT_ROWPAD;
#pragma unroll
    for (int k = 0; k < D; ++k) wr[k] = 0.0f;
#pragma unroll
    for (int j = 0; j < WINDOW; ++j) wr[start + j] = acc[j];
    __syncthreads();   // cross-lane before coalesced store

    // ---- stage-out: 480 contiguous float4, fully coalesced ----
    float4* gout = reinterpret_cast<float4*>(out);
#pragma unroll
    for (int it = 0; it < 8; ++it) {
        const int g = it * 64 + lane;
        if (g < 480 && f4base + g < f4lim) {
            const int pair = g / 15, within = g - pair * 15;
            const int r0 = pair * 2, f0 = within * 4;
            float vv[4];
#pragma unroll
            for (int e = 0; e < 4; ++e) {
                const int ff = f0 + e;
                const int r  = r0 + (ff >= D);
                const int c  = ff - ((ff >= D) ? D : 0);
                vv[e] = ws[r * OT_ROWPAD + c];
            }
            gout[f4base + g] = make_float4(vv[0], vv[1], vv[2], vv[3]);
        }
    }
}

// ===========================================================================
// Fallback (atomic path) if buffers are unexpectedly small.
// ===========================================================================
#define SAME_INC (1u << 12)
#define DIFF_INC (1u << 22)

__global__ __launch_bounds__(256) void edge_pass_atomic(
    const int* __restrict__ edge_index, const int* __restrict__ atom_types,
    unsigned* __restrict__ agg)
{
    const int t  = blockIdx.x * blockDim.x + threadIdx.x;
    const int e0 = t * 4;
    if (e0 >= N_EDGES) return;
    const int4 s4 = *reinterpret_cast<const int4*>(edge_index + e0);
    const int4 d4 = *reinterpret_cast<const int4*>(edge_index + N_EDGES + e0);
    const int ss[4] = {s4.x, s4.y, s4.z, s4.w};
    const int dd[4] = {d4.x, d4.y, d4.z, d4.w};
#pragma unroll
    for (int k = 0; k < 4; ++k) {
        const int s = ss[k], d = dd[k];
        const unsigned add = 1u + ((atom_types[s] == atom_types[d]) ? SAME_INC : DIFF_INC);
        atomicAdd(agg + s, add);
        atomicAdd(agg + d, add);
    }
}

__global__ __launch_bounds__(256) void out_pass_agg(
    const float* __restrict__ x, const float* __restrict__ Wm,
    const unsigned* __restrict__ agg, const int* __restrict__ atom_types,
    float* __restrict__ out)
{
    __shared__ float sx[64 * D];
    __shared__ float sW[D * D];
    __shared__ int   sstart[64];
    const int tid   = threadIdx.x;
    const long base = (long)blockIdx.x * 64;
    for (int i = tid; i < D * D; i += 256) sW[i] = Wm[i];
    const float* xb = x + base * D;
    for (int i = tid; i < 64 * D; i += 256) sx[i] = xb[i];
    if (tid < 64) {
        const long n = base + tid;
        const unsigned a = agg[n];
        const int cnt = a & 0xFFFu, sc = (a >> 12) & 0x3FFu, dc = a >> 22;
        const int mix  = dc ? 0 : (sc ? atom_types[n] + 1 : 0);
        sstart[tid] = ((cnt > DEG_THRESH ? 3 : 0) + mix) * WINDOW;
    }
    __syncthreads();
    const float scale = 0.18257418583505536f;
    float* ob = out + base * D;
    for (int i = tid; i < 64 * D; i += 256) {
        const int nd = i / D, c = i - nd * D;
        float v = 0.0f;
        if ((unsigned)(c - sstart[nd]) < WINDOW) {
            float acc = 0.0f;
#pragma unroll
            for (int k = 0; k < D; ++k) acc += sx[nd * D + k] * sW[k * D + c];
            v = acc * scale;
        }
        ob[i] = v;
    }
}

// ---------------------------------------------------------------------------
extern "C" void kernel_launch(void* const* d_in, const int* in_sizes, int n_in,
                              void* d_out, int out_size, void* d_ws, size_t ws_size,
                              hipStream_t stream)
{
    const float* x          = (const float*)d_in[0];
    const float* Wm         = (const float*)d_in[1];
    const int*   edge_index = (const int*)d_in[2];
    const int*   atom_types = (const int*)d_in[3];
    float* out = (float*)d_out;

    if (ws_size >= WS_NEEDED && (size_t)out_size * 4 >= OUT_BYTES_NEEDED) {
        char* ws = (char*)d_ws;
        unsigned*       bm       = (unsigned*)(ws + WS_BM_OFF);
        unsigned*       partials = (unsigned*)(ws + WS_PART_OFF);
        unsigned short* buckets  = (unsigned short*)d_out;   // scratch, overwritten
        unsigned*       cellcnt  = (unsigned*)((char*)d_out + CCNT_OFF);

        pack_types<<<(N_NODES + 255) / 256, 256, 0, stream>>>(atom_types, bm);
        bin_edges<<<BIN_BLOCKS, BIN_THREADS, L_TOTAL, stream>>>(edge_index, bm,
                                                                buckets, cellcnt);
        hist_pass<<<P_PARTS * SLICES, 512, 0, stream>>>(buckets, cellcnt, partials);
        out_pass<<<(N_NODES + OT_THREADS - 1) / OT_THREADS, OT_THREADS, 0, stream>>>(
            x, Wm, partials, bm, out);
    } else {
        unsigned* agg = (unsigned*)d_ws;
        hipMemsetAsync(agg, 0x00, N_NODES * sizeof(unsigned), stream);
        edge_pass_atomic<<<(N_EDGES / 4) / 256, 256, 0, stream>>>(edge_index, atom_types, agg);
        out_pass_agg<<<N_NODES / 64, 256, 0, stream>>>(x, Wm, agg, atom_types, out);
    }
}